// Round 1
// baseline (1215.734 us; speedup 1.0000x reference)
//
#include <hip/hip_runtime.h>
#include <hip/hip_bf16.h>

#define NN    100000
#define NE    1600000
#define INCH  512
#define HIDCH 256
#define OUTCH 32
#define KHOPS 10

// ---------------- workspace layout ----------------
constexpr size_t ws_align(size_t x) { return (x + 255) & ~(size_t)255; }
constexpr size_t OFF_H1   = 0;                                          // [NN][256] f32
constexpr size_t OFF_HA   = OFF_H1   + ws_align((size_t)NN*HIDCH*4);    // [NN][32] f32
constexpr size_t OFF_HB   = OFF_HA   + ws_align((size_t)NN*OUTCH*4);    // [NN][32] f32
constexpr size_t OFF_NORM = OFF_HB   + ws_align((size_t)NN*OUTCH*4);    // [NE] f32
constexpr size_t OFF_DEG  = OFF_NORM + ws_align((size_t)NE*4);          // [NN] int
constexpr size_t OFF_DIS  = OFF_DEG  + ws_align((size_t)NN*4);          // [NN] f32
constexpr size_t OFF_RP   = OFF_DIS  + ws_align((size_t)NN*4);          // [NN+1] int
constexpr size_t OFF_CUR  = OFF_RP   + ws_align((size_t)(NN+1)*4);      // [NN] int
constexpr size_t OFF_CSRS = OFF_CUR  + ws_align((size_t)NN*4);          // [NE] int
constexpr size_t OFF_CSRN = OFF_CSRS + ws_align((size_t)NE*4);          // [NE] f32
constexpr size_t OFF_PART = OFF_CSRN + ws_align((size_t)NE*4);          // [128] int
constexpr size_t OFF_OFFS = OFF_PART + ws_align(512);                   // [128] int

// ---------------- degree / norm ----------------
__global__ __launch_bounds__(256) void k_count_deg(const int* __restrict__ col,
                                                   int* __restrict__ deg) {
  int e = blockIdx.x * 256 + threadIdx.x;
  if (e < NE) atomicAdd(&deg[col[e]], 1);
}

__global__ __launch_bounds__(256) void k_dis(const int* __restrict__ deg,
                                             float* __restrict__ dis) {
  int v = blockIdx.x * 256 + threadIdx.x;
  if (v < NN) {
    int d = deg[v];
    dis[v] = d > 0 ? rsqrtf((float)d) : 0.0f;
  }
}

__global__ __launch_bounds__(256) void k_norm(const int* __restrict__ ei,
                                              const float* __restrict__ dis,
                                              float* __restrict__ nrm) {
  int e = blockIdx.x * 256 + threadIdx.x;
  if (e < NE) nrm[e] = dis[ei[e]] * dis[ei[NE + e]];
}

// ---------------- exclusive scan over deg (3 kernels) ----------------
__global__ __launch_bounds__(256) void k_scan1(const int* __restrict__ deg,
                                               int* __restrict__ rp,
                                               int* __restrict__ part) {
  __shared__ int s[256];
  int b = blockIdx.x, t = threadIdx.x;
  int base = b * 1024 + t * 4;
  int v0 = (base + 0 < NN) ? deg[base + 0] : 0;
  int v1 = (base + 1 < NN) ? deg[base + 1] : 0;
  int v2 = (base + 2 < NN) ? deg[base + 2] : 0;
  int v3 = (base + 3 < NN) ? deg[base + 3] : 0;
  int tot = v0 + v1 + v2 + v3;
  s[t] = tot;
  __syncthreads();
  for (int d = 1; d < 256; d <<= 1) {
    int x = (t >= d) ? s[t - d] : 0;
    __syncthreads();
    s[t] += x;
    __syncthreads();
  }
  int excl = s[t] - tot;
  if (t == 255) part[b] = s[255];
  if (base + 0 < NN) rp[base + 0] = excl;
  if (base + 1 < NN) rp[base + 1] = excl + v0;
  if (base + 2 < NN) rp[base + 2] = excl + v0 + v1;
  if (base + 3 < NN) rp[base + 3] = excl + v0 + v1 + v2;
}

__global__ __launch_bounds__(128) void k_scan2(const int* __restrict__ part,
                                               int* __restrict__ offs) {
  __shared__ int s[128];
  int t = threadIdx.x;
  int v = (t < 98) ? part[t] : 0;
  s[t] = v;
  __syncthreads();
  for (int d = 1; d < 128; d <<= 1) {
    int x = (t >= d) ? s[t - d] : 0;
    __syncthreads();
    s[t] += x;
    __syncthreads();
  }
  if (t < 98) offs[t] = s[t] - v;
}

__global__ __launch_bounds__(256) void k_scan3(int* __restrict__ rp,
                                               const int* __restrict__ offs,
                                               int* __restrict__ cur) {
  int b = blockIdx.x, t = threadIdx.x;
  int o = offs[b];
  int base = b * 1024 + t * 4;
#pragma unroll
  for (int j = 0; j < 4; ++j) {
    int i = base + j;
    if (i < NN) {
      int r = rp[i] + o;
      rp[i] = r;
      cur[i] = r;
    }
  }
  if (b == 0 && t == 0) rp[NN] = NE;
}

__global__ __launch_bounds__(256) void k_fill(const int* __restrict__ ei,
                                              const float* __restrict__ nrm,
                                              int* __restrict__ cur,
                                              int* __restrict__ csrc,
                                              float* __restrict__ cnrm) {
  int e = blockIdx.x * 256 + threadIdx.x;
  if (e < NE) {
    int c = ei[NE + e];
    int p = atomicAdd(&cur[c], 1);
    csrc[p] = ei[e];
    cnrm[p] = nrm[e];
  }
}

// ---------------- GEMM1: H1 = relu(X @ W1 + b1)  [NN,512]x[512,256] ----------------
__global__ __launch_bounds__(256) void k_gemm1(const float* __restrict__ X,
                                               const float* __restrict__ W1,
                                               const float* __restrict__ bias1,
                                               float* __restrict__ H1) {
  __shared__ __align__(16) float As[16][132];  // transposed A tile [k][m], pad 4
  __shared__ __align__(16) float Bs[16][128];  // [k][n]
  const int t = threadIdx.x;
  const int m0 = blockIdx.x * 128;
  const int n0 = blockIdx.y * 128;
  const int tm = t >> 4, tn = t & 15;
  // A staging: rows ar, ar+64; 16-col tile as 4 float4 chunks
  const int ar = t >> 2, ac = (t & 3) * 4;
  // B staging: rows br, br+8; 128-col tile as 32 float4 chunks
  const int br = t >> 5, bc = (t & 31) * 4;
  float acc[8][8] = {};
  for (int k0 = 0; k0 < INCH; k0 += 16) {
    float4 a0v = make_float4(0.f, 0.f, 0.f, 0.f), a1v = a0v;
    int r0 = m0 + ar, r1 = m0 + ar + 64;
    if (r0 < NN) a0v = *(const float4*)&X[(size_t)r0 * INCH + k0 + ac];
    if (r1 < NN) a1v = *(const float4*)&X[(size_t)r1 * INCH + k0 + ac];
    float4 b0v = *(const float4*)&W1[(size_t)(k0 + br) * HIDCH + n0 + bc];
    float4 b1v = *(const float4*)&W1[(size_t)(k0 + br + 8) * HIDCH + n0 + bc];
    __syncthreads();
    As[ac + 0][ar] = a0v.x; As[ac + 1][ar] = a0v.y;
    As[ac + 2][ar] = a0v.z; As[ac + 3][ar] = a0v.w;
    As[ac + 0][ar + 64] = a1v.x; As[ac + 1][ar + 64] = a1v.y;
    As[ac + 2][ar + 64] = a1v.z; As[ac + 3][ar + 64] = a1v.w;
    *(float4*)&Bs[br][bc] = b0v;
    *(float4*)&Bs[br + 8][bc] = b1v;
    __syncthreads();
#pragma unroll
    for (int kk = 0; kk < 16; ++kk) {
      const float4 a0 = *(const float4*)&As[kk][tm * 8];
      const float4 a1 = *(const float4*)&As[kk][tm * 8 + 4];
      const float4 b0 = *(const float4*)&Bs[kk][tn * 8];
      const float4 b1 = *(const float4*)&Bs[kk][tn * 8 + 4];
      const float av[8] = {a0.x, a0.y, a0.z, a0.w, a1.x, a1.y, a1.z, a1.w};
      const float bv[8] = {b0.x, b0.y, b0.z, b0.w, b1.x, b1.y, b1.z, b1.w};
#pragma unroll
      for (int i = 0; i < 8; ++i)
#pragma unroll
        for (int j = 0; j < 8; ++j)
          acc[i][j] = fmaf(av[i], bv[j], acc[i][j]);
    }
  }
#pragma unroll
  for (int i = 0; i < 8; ++i) {
    int r = m0 + tm * 8 + i;
    if (r < NN) {
#pragma unroll
      for (int j = 0; j < 8; j += 4) {
        int cg = n0 + tn * 8 + j;
        float4 o;
        o.x = fmaxf(acc[i][j + 0] + bias1[cg + 0], 0.f);
        o.y = fmaxf(acc[i][j + 1] + bias1[cg + 1], 0.f);
        o.z = fmaxf(acc[i][j + 2] + bias1[cg + 2], 0.f);
        o.w = fmaxf(acc[i][j + 3] + bias1[cg + 3], 0.f);
        *(float4*)&H1[(size_t)r * HIDCH + cg] = o;
      }
    }
  }
}

// ---------------- GEMM2: h = H1 @ W2 + b2; hA = h; out = gamma[0]*h ----------------
__global__ __launch_bounds__(256) void k_gemm2(const float* __restrict__ H1,
                                               const float* __restrict__ W2,
                                               const float* __restrict__ bias2,
                                               const float* __restrict__ gamma,
                                               float* __restrict__ hA,
                                               float* __restrict__ out) {
  __shared__ __align__(16) float w2s[HIDCH * OUTCH];  // 32 KB
  __shared__ __align__(16) float h1s[8][HIDCH];       // 8 KB
  const int t = threadIdx.x;
  for (int q = t; q < HIDCH * OUTCH / 4; q += 256)
    ((float4*)w2s)[q] = ((const float4*)W2)[q];
  const size_t rowbase4 = (size_t)blockIdx.x * 8 * HIDCH / 4;
  for (int q = t; q < 8 * HIDCH / 4; q += 256)
    ((float4*)&h1s[0][0])[q] = ((const float4*)H1)[rowbase4 + q];
  __syncthreads();
  const int ln = t >> 5, c = t & 31;
  float acc = bias2[c];
#pragma unroll 8
  for (int i = 0; i < HIDCH; ++i)
    acc = fmaf(h1s[ln][i], w2s[i * OUTCH + c], acc);
  const int v = blockIdx.x * 8 + ln;
  hA[(size_t)v * OUTCH + c] = acc;
  out[(size_t)v * OUTCH + c] = gamma[0] * acc;
}

// ---------------- one propagation hop + gamma accumulation ----------------
__global__ __launch_bounds__(256) void k_hop(const float* __restrict__ hin,
                                             float* __restrict__ hout,
                                             float* __restrict__ out,
                                             const int* __restrict__ rp,
                                             const int* __restrict__ csrc,
                                             const float* __restrict__ cnrm,
                                             const float* __restrict__ gamma,
                                             int k) {
  const int v = blockIdx.x * 8 + (threadIdx.x >> 5);
  const int c = threadIdx.x & 31;
  const float g = gamma[k];
  const int s = rp[v], e = rp[v + 1];
  float acc = 0.f;
  int j = s;
  for (; j + 1 < e; j += 2) {
    int s0 = csrc[j], s1 = csrc[j + 1];
    float n0 = cnrm[j], n1 = cnrm[j + 1];
    acc += n0 * hin[(size_t)s0 * OUTCH + c] + n1 * hin[(size_t)s1 * OUTCH + c];
  }
  if (j < e) acc += cnrm[j] * hin[(size_t)csrc[j] * OUTCH + c];
  hout[(size_t)v * OUTCH + c] = acc;
  out[(size_t)v * OUTCH + c] += g * acc;
}

extern "C" void kernel_launch(void* const* d_in, const int* in_sizes, int n_in,
                              void* d_out, int out_size, void* d_ws, size_t ws_size,
                              hipStream_t stream) {
  const float* x     = (const float*)d_in[0];
  const int*   ei    = (const int*)d_in[1];
  const float* W1    = (const float*)d_in[2];
  const float* b1    = (const float*)d_in[3];
  const float* W2    = (const float*)d_in[4];
  const float* b2    = (const float*)d_in[5];
  const float* gamma = (const float*)d_in[6];
  float* out = (float*)d_out;

  char* ws = (char*)d_ws;
  float* h1   = (float*)(ws + OFF_H1);
  float* hA   = (float*)(ws + OFF_HA);
  float* hB   = (float*)(ws + OFF_HB);
  float* nrm  = (float*)(ws + OFF_NORM);
  int*   deg  = (int*)(ws + OFF_DEG);
  float* dis  = (float*)(ws + OFF_DIS);
  int*   rp   = (int*)(ws + OFF_RP);
  int*   cur  = (int*)(ws + OFF_CUR);
  int*   csrc = (int*)(ws + OFF_CSRS);
  float* cnrm = (float*)(ws + OFF_CSRN);
  int*   part = (int*)(ws + OFF_PART);
  int*   offs = (int*)(ws + OFF_OFFS);

  hipMemsetAsync(deg, 0, NN * sizeof(int), stream);

  k_count_deg<<<(NE + 255) / 256, 256, 0, stream>>>(ei + NE, deg);
  k_dis<<<(NN + 255) / 256, 256, 0, stream>>>(deg, dis);
  k_norm<<<(NE + 255) / 256, 256, 0, stream>>>(ei, dis, nrm);
  k_scan1<<<98, 256, 0, stream>>>(deg, rp, part);
  k_scan2<<<1, 128, 0, stream>>>(part, offs);
  k_scan3<<<98, 256, 0, stream>>>(rp, offs, cur);
  k_fill<<<(NE + 255) / 256, 256, 0, stream>>>(ei, nrm, cur, csrc, cnrm);

  k_gemm1<<<dim3((NN + 127) / 128, HIDCH / 128), 256, 0, stream>>>(x, W1, b1, h1);
  k_gemm2<<<NN / 8, 256, 0, stream>>>(h1, W2, b2, gamma, hA, out);

  float* hin = hA;
  float* hout = hB;
  for (int k = 1; k <= KHOPS; ++k) {
    k_hop<<<NN / 8, 256, 0, stream>>>(hin, hout, out, rp, csrc, cnrm, gamma, k);
    float* tmp = hin; hin = hout; hout = tmp;
  }
}

// Round 2
// 747.253 us; speedup vs baseline: 1.6269x; 1.6269x over previous
//
#include <hip/hip_runtime.h>
#include <hip/hip_bf16.h>

#define NN    100000
#define NE    1600000
#define INCH  512
#define HIDCH 256
#define OUTCH 32
#define KHOPS 10

typedef __attribute__((ext_vector_type(8))) short short8;
typedef __attribute__((ext_vector_type(4))) float f32x4;

// ---------------- workspace layout ----------------
constexpr size_t ws_align(size_t x) { return (x + 255) & ~(size_t)255; }
constexpr size_t OFF_H1   = 0;                                           // [NN][256] bf16
constexpr size_t OFF_HA   = OFF_H1   + ws_align((size_t)NN*HIDCH*2);     // [NN][32] f32
constexpr size_t OFF_HB   = OFF_HA   + ws_align((size_t)NN*OUTCH*4);     // [NN][32] f32
constexpr size_t OFF_W1TH = OFF_HB   + ws_align((size_t)NN*OUTCH*4);     // [256][512] bf16
constexpr size_t OFF_W1TL = OFF_W1TH + ws_align((size_t)HIDCH*INCH*2);
constexpr size_t OFF_W2TH = OFF_W1TL + ws_align((size_t)HIDCH*INCH*2);   // [32][256] bf16
constexpr size_t OFF_W2TL = OFF_W2TH + ws_align((size_t)OUTCH*HIDCH*2);
constexpr size_t OFF_DEG  = OFF_W2TL + ws_align((size_t)OUTCH*HIDCH*2);  // [NN] int
constexpr size_t OFF_DIS  = OFF_DEG  + ws_align((size_t)NN*4);           // [NN] f32
constexpr size_t OFF_RP   = OFF_DIS  + ws_align((size_t)NN*4);           // [NN+1] int
constexpr size_t OFF_CUR  = OFF_RP   + ws_align((size_t)(NN+1)*4);       // [NN] int
constexpr size_t OFF_CSRS = OFF_CUR  + ws_align((size_t)NN*4);           // [NE] int
constexpr size_t OFF_CSRN = OFF_CSRS + ws_align((size_t)NE*4);           // [NE] f32
constexpr size_t OFF_PART = OFF_CSRN + ws_align((size_t)NE*4);           // [128] int
constexpr size_t OFF_OFFS = OFF_PART + ws_align(512);                    // [128] int

// ---------------- bf16 helpers ----------------
__device__ __forceinline__ unsigned short bf16_rne(float f) {
  unsigned int u = __float_as_uint(f);
  u += 0x7fffu + ((u >> 16) & 1u);
  return (unsigned short)(u >> 16);
}
__device__ __forceinline__ float bf16_to_f32(unsigned short h) {
  return __uint_as_float(((unsigned int)h) << 16);
}

// ---------------- degree / norm ----------------
__global__ __launch_bounds__(256) void k_count_deg(const int* __restrict__ col,
                                                   int* __restrict__ deg) {
  int e = blockIdx.x * 256 + threadIdx.x;
  if (e < NE) atomicAdd(&deg[col[e]], 1);
}

__global__ __launch_bounds__(256) void k_dis(const int* __restrict__ deg,
                                             float* __restrict__ dis) {
  int v = blockIdx.x * 256 + threadIdx.x;
  if (v < NN) {
    int d = deg[v];
    dis[v] = d > 0 ? rsqrtf((float)d) : 0.0f;
  }
}

// ---------------- exclusive scan over deg (3 kernels) ----------------
__global__ __launch_bounds__(256) void k_scan1(const int* __restrict__ deg,
                                               int* __restrict__ rp,
                                               int* __restrict__ part) {
  __shared__ int s[256];
  int b = blockIdx.x, t = threadIdx.x;
  int base = b * 1024 + t * 4;
  int v0 = (base + 0 < NN) ? deg[base + 0] : 0;
  int v1 = (base + 1 < NN) ? deg[base + 1] : 0;
  int v2 = (base + 2 < NN) ? deg[base + 2] : 0;
  int v3 = (base + 3 < NN) ? deg[base + 3] : 0;
  int tot = v0 + v1 + v2 + v3;
  s[t] = tot;
  __syncthreads();
  for (int d = 1; d < 256; d <<= 1) {
    int x = (t >= d) ? s[t - d] : 0;
    __syncthreads();
    s[t] += x;
    __syncthreads();
  }
  int excl = s[t] - tot;
  if (t == 255) part[b] = s[255];
  if (base + 0 < NN) rp[base + 0] = excl;
  if (base + 1 < NN) rp[base + 1] = excl + v0;
  if (base + 2 < NN) rp[base + 2] = excl + v0 + v1;
  if (base + 3 < NN) rp[base + 3] = excl + v0 + v1 + v2;
}

__global__ __launch_bounds__(128) void k_scan2(const int* __restrict__ part,
                                               int* __restrict__ offs) {
  __shared__ int s[128];
  int t = threadIdx.x;
  int v = (t < 98) ? part[t] : 0;
  s[t] = v;
  __syncthreads();
  for (int d = 1; d < 128; d <<= 1) {
    int x = (t >= d) ? s[t - d] : 0;
    __syncthreads();
    s[t] += x;
    __syncthreads();
  }
  if (t < 98) offs[t] = s[t] - v;
}

__global__ __launch_bounds__(256) void k_scan3(int* __restrict__ rp,
                                               const int* __restrict__ offs,
                                               int* __restrict__ cur) {
  int b = blockIdx.x, t = threadIdx.x;
  int o = offs[b];
  int base = b * 1024 + t * 4;
#pragma unroll
  for (int j = 0; j < 4; ++j) {
    int i = base + j;
    if (i < NN) {
      int r = rp[i] + o;
      rp[i] = r;
      cur[i] = r;
    }
  }
  if (b == 0 && t == 0) rp[NN] = NE;
}

// fill CSR: csrc = source node, cnrm = dis[row]*dis[col] (norm fused in)
__global__ __launch_bounds__(256) void k_fill(const int* __restrict__ ei,
                                              const float* __restrict__ dis,
                                              int* __restrict__ cur,
                                              int* __restrict__ csrc,
                                              float* __restrict__ cnrm) {
  int e = blockIdx.x * 256 + threadIdx.x;
  if (e < NE) {
    int r = ei[e], c = ei[NE + e];
    int p = atomicAdd(&cur[c], 1);
    csrc[p] = r;
    cnrm[p] = dis[r] * dis[c];
  }
}

// ---------------- split-transpose: dst[n][k] = split(src[k][n]) ----------------
__global__ __launch_bounds__(256) void k_splitT(const float* __restrict__ src,
                                                unsigned short* __restrict__ dh,
                                                unsigned short* __restrict__ dl,
                                                int K, int N) {
  int idx = blockIdx.x * 256 + threadIdx.x;
  if (idx >= K * N) return;
  int n = idx / K, k = idx - n * K;
  float v = src[(size_t)k * N + n];
  unsigned short h = bf16_rne(v);
  dh[idx] = h;
  dl[idx] = bf16_rne(v - bf16_to_f32(h));
}

// ---------------- GEMM1: H1bf = bf16(relu(X @ W1 + b1)) via 3-product bf16 MFMA ----
// tile 128(M) x 256(N=all) x 32(K-step); 8 waves (2M x 4N), wave tile 64x64
__global__ __launch_bounds__(512, 2) void k_gemm1(const float* __restrict__ X,
                                                  const unsigned short* __restrict__ W1Th,
                                                  const unsigned short* __restrict__ W1Tl,
                                                  const float* __restrict__ bias1,
                                                  unsigned short* __restrict__ H1bf) {
  // frag-packed LDS: per 16-row group g, slot = g*64 + lane, 16B per slot
  __shared__ __align__(16) unsigned short Ah[4096], Al[4096];   // 8 groups
  __shared__ __align__(16) unsigned short Bh[8192], Bl[8192];   // 16 groups
  const int t = threadIdx.x;
  const int m0 = blockIdx.x * 128;

  // A staging: thread t -> row t/4, kq (t%4)*8 : 8 consecutive f32 of one row
  const int arow = t >> 2;
  const int akq  = (t & 3) * 8;
  int axrow = m0 + arow; if (axrow >= NN) axrow = NN - 1;
  const float* aptr = X + (size_t)axrow * INCH + akq;
  const int a_lds = (arow >> 4) * 512 + ((arow & 15) + ((akq >> 3) << 4)) * 8;

  // B staging: thread t -> n-row t/2, two 8-k chunks at kq=(t%2)*16 + {0,8}
  const int bn  = t >> 1;
  const int bkq = (t & 1) * 16;
  const int b_lds0 = (bn >> 4) * 512 + ((bn & 15) + ((bkq >> 3) << 4)) * 8;
  const int b_lds1 = b_lds0 + 128;  // next k-chunk: lane+16 -> +16*8 ushorts
  const unsigned short* bhp = W1Th + (size_t)bn * INCH + bkq;
  const unsigned short* blp = W1Tl + (size_t)bn * INCH + bkq;

  const int w = t >> 6, lane = t & 63;
  const int wm = w >> 2, wn = w & 3;

  f32x4 acc[4][4] = {};

  for (int k0 = 0; k0 < INCH; k0 += 32) {
    float4 av0 = *(const float4*)(aptr + k0);
    float4 av1 = *(const float4*)(aptr + k0 + 4);
    uint4 bh0 = *(const uint4*)(bhp + k0);
    uint4 bh1 = *(const uint4*)(bhp + k0 + 8);
    uint4 bl0 = *(const uint4*)(blp + k0);
    uint4 bl1 = *(const uint4*)(blp + k0 + 8);

    __syncthreads();

    {
      float af[8] = {av0.x, av0.y, av0.z, av0.w, av1.x, av1.y, av1.z, av1.w};
      short8 ah, al;
#pragma unroll
      for (int i = 0; i < 8; ++i) {
        unsigned int u = __float_as_uint(af[i]);
        unsigned int h = (u + 0x7fffu + ((u >> 16) & 1u)) >> 16;
        float lof = af[i] - __uint_as_float(h << 16);
        unsigned int ul = __float_as_uint(lof);
        unsigned int l = (ul + 0x7fffu + ((ul >> 16) & 1u)) >> 16;
        ah[i] = (short)h;
        al[i] = (short)l;
      }
      *(short8*)&Ah[a_lds] = ah;
      *(short8*)&Al[a_lds] = al;
    }
    *(uint4*)&Bh[b_lds0] = bh0;
    *(uint4*)&Bh[b_lds1] = bh1;
    *(uint4*)&Bl[b_lds0] = bl0;
    *(uint4*)&Bl[b_lds1] = bl1;

    __syncthreads();

    const short8* AhV = (const short8*)Ah;
    const short8* AlV = (const short8*)Al;
    const short8* BhV = (const short8*)Bh;
    const short8* BlV = (const short8*)Bl;
    short8 afh[4], afl[4];
#pragma unroll
    for (int mf = 0; mf < 4; ++mf) {
      afh[mf] = AhV[(wm * 4 + mf) * 64 + lane];
      afl[mf] = AlV[(wm * 4 + mf) * 64 + lane];
    }
#pragma unroll
    for (int nf = 0; nf < 4; ++nf) {
      short8 bfh = BhV[(wn * 4 + nf) * 64 + lane];
      short8 bfl = BlV[(wn * 4 + nf) * 64 + lane];
#pragma unroll
      for (int mf = 0; mf < 4; ++mf) {
        acc[mf][nf] = __builtin_amdgcn_mfma_f32_16x16x32_bf16(afh[mf], bfh, acc[mf][nf], 0, 0, 0);
        acc[mf][nf] = __builtin_amdgcn_mfma_f32_16x16x32_bf16(afh[mf], bfl, acc[mf][nf], 0, 0, 0);
        acc[mf][nf] = __builtin_amdgcn_mfma_f32_16x16x32_bf16(afl[mf], bfh, acc[mf][nf], 0, 0, 0);
      }
    }
  }

  // epilogue: +bias, relu, cvt bf16, store
  const int colbase = wn * 64 + (lane & 15);
  const int rowbase = m0 + wm * 64 + ((lane >> 4) << 2);
#pragma unroll
  for (int nf = 0; nf < 4; ++nf) {
    int col = colbase + nf * 16;
    float b = bias1[col];
#pragma unroll
    for (int mf = 0; mf < 4; ++mf) {
#pragma unroll
      for (int r = 0; r < 4; ++r) {
        int row = rowbase + mf * 16 + r;
        if (row < NN) {
          float h = fmaxf(acc[mf][nf][r] + b, 0.f);
          H1bf[(size_t)row * HIDCH + col] = bf16_rne(h);
        }
      }
    }
  }
}

// ---------------- GEMM2: h = H1bf @ W2 + b2 (2-product on W2); hA = h; out = g0*h --
// tile 128(M) x 32(N) x 64(K-step); 4 waves, wave tile 32x32
__global__ __launch_bounds__(256) void k_gemm2(const unsigned short* __restrict__ H1bf,
                                               const unsigned short* __restrict__ W2Th,
                                               const unsigned short* __restrict__ W2Tl,
                                               const float* __restrict__ bias2,
                                               const float* __restrict__ gamma,
                                               float* __restrict__ hA,
                                               float* __restrict__ out) {
  __shared__ __align__(16) unsigned short A2[8192];             // 8 m-groups x 2 k32
  __shared__ __align__(16) unsigned short B2h[2048], B2l[2048]; // 2 n-groups x 2 k32
  const int t = threadIdx.x;
  const int m0 = blockIdx.x * 128;

  const int arow = t >> 1;
  int axrow = m0 + arow; if (axrow >= NN) axrow = NN - 1;
  const int akb = (t & 1) * 32;
  const unsigned short* ap = H1bf + (size_t)axrow * HIDCH + akb;
  const int abase = ((arow >> 4) * 2 + (akb >> 5)) * 512 + (arow & 15) * 8;

  const int bnr = t >> 3, bkq = (t & 7) * 8;
  const int bslot = ((bnr >> 4) * 2 + (bkq >> 5)) * 512 +
                    ((bnr & 15) + (((bkq & 31) >> 3) << 4)) * 8;
  const unsigned short* bhp = W2Th + (size_t)bnr * HIDCH + bkq;
  const unsigned short* blp = W2Tl + (size_t)bnr * HIDCH + bkq;

  const int w = t >> 6, lane = t & 63;

  f32x4 acc[2][2] = {};

  for (int k0 = 0; k0 < HIDCH; k0 += 64) {
    uint4 a0 = *(const uint4*)(ap + k0);
    uint4 a1 = *(const uint4*)(ap + k0 + 8);
    uint4 a2 = *(const uint4*)(ap + k0 + 16);
    uint4 a3 = *(const uint4*)(ap + k0 + 24);
    uint4 bh = *(const uint4*)(bhp + k0);
    uint4 bl = *(const uint4*)(blp + k0);

    __syncthreads();

    *(uint4*)&A2[abase + 0 * 128] = a0;
    *(uint4*)&A2[abase + 1 * 128] = a1;
    *(uint4*)&A2[abase + 2 * 128] = a2;
    *(uint4*)&A2[abase + 3 * 128] = a3;
    *(uint4*)&B2h[bslot] = bh;
    *(uint4*)&B2l[bslot] = bl;

    __syncthreads();

    const short8* AV  = (const short8*)A2;
    const short8* BHV = (const short8*)B2h;
    const short8* BLV = (const short8*)B2l;
#pragma unroll
    for (int k32 = 0; k32 < 2; ++k32) {
      short8 bfh[2], bfl[2];
#pragma unroll
      for (int nf = 0; nf < 2; ++nf) {
        bfh[nf] = BHV[(nf * 2 + k32) * 64 + lane];
        bfl[nf] = BLV[(nf * 2 + k32) * 64 + lane];
      }
#pragma unroll
      for (int mf = 0; mf < 2; ++mf) {
        short8 a = AV[((w * 2 + mf) * 2 + k32) * 64 + lane];
#pragma unroll
        for (int nf = 0; nf < 2; ++nf) {
          acc[mf][nf] = __builtin_amdgcn_mfma_f32_16x16x32_bf16(a, bfh[nf], acc[mf][nf], 0, 0, 0);
          acc[mf][nf] = __builtin_amdgcn_mfma_f32_16x16x32_bf16(a, bfl[nf], acc[mf][nf], 0, 0, 0);
        }
      }
    }
  }

  const float g0 = gamma[0];
  const int colb = lane & 15;
  const int rowb = m0 + w * 32 + ((lane >> 4) << 2);
#pragma unroll
  for (int nf = 0; nf < 2; ++nf) {
    int col = nf * 16 + colb;
    float b = bias2[col];
#pragma unroll
    for (int mf = 0; mf < 2; ++mf) {
#pragma unroll
      for (int r = 0; r < 4; ++r) {
        int row = rowb + mf * 16 + r;
        if (row < NN) {
          float h = acc[mf][nf][r] + b;
          hA[(size_t)row * OUTCH + col] = h;
          out[(size_t)row * OUTCH + col] = g0 * h;
        }
      }
    }
  }
}

// ---------------- one propagation hop + gamma accumulation ----------------
// wave handles 2 nodes (half-wave each); edge indices loaded lane-parallel
// (coalesced 128B per 32 edges) then broadcast via shfl; gathers independent.
__global__ __launch_bounds__(256) void k_hop(const float* __restrict__ hin,
                                             float* __restrict__ hout,
                                             float* __restrict__ out,
                                             const int* __restrict__ rp,
                                             const int* __restrict__ csrc,
                                             const float* __restrict__ cnrm,
                                             const float* __restrict__ gamma,
                                             int k) {
  const int wid  = threadIdx.x >> 6;
  const int lane = threadIdx.x & 63;
  const int half = lane >> 5;
  const int c    = lane & 31;
  const int v = blockIdx.x * 8 + wid * 2 + half;
  const float g = gamma[k];
  const int s = rp[v], e = rp[v + 1];
  const int sbase = half << 5;
  float acc0 = 0.f, acc1 = 0.f;
  for (int base = s; base < e; base += 32) {
    int nidx = base + c;
    bool valid = nidx < e;
    int   srcv = valid ? csrc[nidx] : 0;
    float nrmv = valid ? cnrm[nidx] : 0.f;
    int cnt = min(32, e - base);
    int j = 0;
    for (; j + 2 <= cnt; j += 2) {
      int   s0 = __shfl(srcv, sbase + j);
      int   s1 = __shfl(srcv, sbase + j + 1);
      float n0 = __shfl(nrmv, sbase + j);
      float n1 = __shfl(nrmv, sbase + j + 1);
      acc0 = fmaf(n0, hin[(size_t)s0 * OUTCH + c], acc0);
      acc1 = fmaf(n1, hin[(size_t)s1 * OUTCH + c], acc1);
    }
    if (j < cnt) {
      int   s0 = __shfl(srcv, sbase + j);
      float n0 = __shfl(nrmv, sbase + j);
      acc0 = fmaf(n0, hin[(size_t)s0 * OUTCH + c], acc0);
    }
  }
  float acc = acc0 + acc1;
  hout[(size_t)v * OUTCH + c] = acc;
  out[(size_t)v * OUTCH + c] += g * acc;
}

extern "C" void kernel_launch(void* const* d_in, const int* in_sizes, int n_in,
                              void* d_out, int out_size, void* d_ws, size_t ws_size,
                              hipStream_t stream) {
  const float* x     = (const float*)d_in[0];
  const int*   ei    = (const int*)d_in[1];
  const float* W1    = (const float*)d_in[2];
  const float* b1    = (const float*)d_in[3];
  const float* W2    = (const float*)d_in[4];
  const float* b2    = (const float*)d_in[5];
  const float* gamma = (const float*)d_in[6];
  float* out = (float*)d_out;

  char* ws = (char*)d_ws;
  unsigned short* h1bf = (unsigned short*)(ws + OFF_H1);
  float* hA   = (float*)(ws + OFF_HA);
  float* hB   = (float*)(ws + OFF_HB);
  unsigned short* w1th = (unsigned short*)(ws + OFF_W1TH);
  unsigned short* w1tl = (unsigned short*)(ws + OFF_W1TL);
  unsigned short* w2th = (unsigned short*)(ws + OFF_W2TH);
  unsigned short* w2tl = (unsigned short*)(ws + OFF_W2TL);
  int*   deg  = (int*)(ws + OFF_DEG);
  float* dis  = (float*)(ws + OFF_DIS);
  int*   rp   = (int*)(ws + OFF_RP);
  int*   cur  = (int*)(ws + OFF_CUR);
  int*   csrc = (int*)(ws + OFF_CSRS);
  float* cnrm = (float*)(ws + OFF_CSRN);
  int*   part = (int*)(ws + OFF_PART);
  int*   offs = (int*)(ws + OFF_OFFS);

  hipMemsetAsync(deg, 0, NN * sizeof(int), stream);

  // weight prep (tiny)
  k_splitT<<<(INCH * HIDCH + 255) / 256, 256, 0, stream>>>(W1, w1th, w1tl, INCH, HIDCH);
  k_splitT<<<(HIDCH * OUTCH + 255) / 256, 256, 0, stream>>>(W2, w2th, w2tl, HIDCH, OUTCH);

  // graph prep
  k_count_deg<<<(NE + 255) / 256, 256, 0, stream>>>(ei + NE, deg);
  k_dis<<<(NN + 255) / 256, 256, 0, stream>>>(deg, dis);
  k_scan1<<<98, 256, 0, stream>>>(deg, rp, part);
  k_scan2<<<1, 128, 0, stream>>>(part, offs);
  k_scan3<<<98, 256, 0, stream>>>(rp, offs, cur);
  k_fill<<<(NE + 255) / 256, 256, 0, stream>>>(ei, dis, cur, csrc, cnrm);

  // MLP
  k_gemm1<<<(NN + 127) / 128, 512, 0, stream>>>(x, w1th, w1tl, b1, h1bf);
  k_gemm2<<<(NN + 127) / 128, 256, 0, stream>>>(h1bf, w2th, w2tl, b2, gamma, hA, out);

  // propagation
  float* hin = hA;
  float* hout = hB;
  for (int k = 1; k <= KHOPS; ++k) {
    k_hop<<<NN / 8, 256, 0, stream>>>(hin, hout, out, rp, csrc, cnrm, gamma, k);
    float* tmp = hin; hin = hout; hout = tmp;
  }
}